// Round 1
// baseline (803.203 us; speedup 1.0000x reference)
//
#include <hip/hip_runtime.h>

typedef unsigned short u16;
typedef unsigned int   u32;

#define T_TOK 2048
#define DIM   2048
#define FDIM  1408
#define NEXP  8

typedef __bf16 bf16x8 __attribute__((ext_vector_type(8)));
typedef float  f32x4  __attribute__((ext_vector_type(4)));

union B16 { uint4 u; bf16x8 v; };

__device__ __forceinline__ u16 f2bf(float f) {
  union { float f; u32 u; } c; c.f = f;
  u32 u = c.u;
  u += 0x7FFFu + ((u >> 16) & 1u);   // round-to-nearest-even
  return (u16)(u >> 16);
}

// ---------------- router: fp32 logits, softmax top-2 renormalized ----------------
__global__ __launch_bounds__(256) void router_kernel(
    const float* __restrict__ x, const float* __restrict__ gate_w,
    int* __restrict__ sel, float* __restrict__ wgt, int* __restrict__ counts)
{
  const int t = blockIdx.x;
  const float* xr = x + (size_t)t * DIM;
  float acc[NEXP];
  #pragma unroll
  for (int e = 0; e < NEXP; ++e) acc[e] = 0.f;
  for (int d = threadIdx.x; d < DIM; d += 256) {
    float xv = xr[d];
    #pragma unroll
    for (int e = 0; e < NEXP; ++e) acc[e] += xv * gate_w[e * DIM + d];
  }
  #pragma unroll
  for (int e = 0; e < NEXP; ++e) {
    #pragma unroll
    for (int s = 32; s > 0; s >>= 1) acc[e] += __shfl_down(acc[e], s, 64);
  }
  __shared__ float red[4][NEXP];
  const int lane = threadIdx.x & 63, wv = threadIdx.x >> 6;
  if (lane == 0) {
    #pragma unroll
    for (int e = 0; e < NEXP; ++e) red[wv][e] = acc[e];
  }
  __syncthreads();
  if (threadIdx.x == 0) {
    float l[NEXP];
    #pragma unroll
    for (int e = 0; e < NEXP; ++e) l[e] = red[0][e] + red[1][e] + red[2][e] + red[3][e];
    int i0 = 0;
    #pragma unroll
    for (int e = 1; e < NEXP; ++e) if (l[e] > l[i0]) i0 = e;   // lowest index wins ties
    int i1 = (i0 == 0) ? 1 : 0;
    #pragma unroll
    for (int e = 0; e < NEXP; ++e) if (e != i0 && l[e] > l[i1]) i1 = e;
    // renormalized top-2 softmax weights: p0/(p0+p1) = 1/(1+exp(l1-l0))
    float w0 = 1.f / (1.f + __expf(l[i1] - l[i0]));
    sel[t * 2] = i0; sel[t * 2 + 1] = i1;
    wgt[t * 2] = w0; wgt[t * 2 + 1] = 1.f - w0;
    atomicAdd(&counts[i0], 1);
    atomicAdd(&counts[i1], 1);
  }
}

// ---------------- tiny scan: counts -> segment offsets ----------------
__global__ void scan_kernel(const int* __restrict__ counts, int* __restrict__ offs)
{
  if (threadIdx.x == 0) {
    int s = 0;
    for (int e = 0; e < NEXP; ++e) { offs[e] = s; s += counts[e]; }
    offs[NEXP] = s;
  }
}

// ---------------- gather: slot assignment + x -> bf16 segments ----------------
__global__ __launch_bounds__(256) void gather_kernel(
    const float* __restrict__ x, const int* __restrict__ sel, const float* __restrict__ wgt,
    const int* __restrict__ offs, int* __restrict__ fill,
    int* __restrict__ slot_token, float* __restrict__ slot_w, u16* __restrict__ Xg)
{
  const int id = blockIdx.x;       // t*2 + k
  const int t = id >> 1;
  __shared__ int s_slot;
  if (threadIdx.x == 0) {
    int e = sel[id];
    int pos = atomicAdd(&fill[e], 1);
    int slot = offs[e] + pos;
    s_slot = slot;
    slot_token[slot] = t;
    slot_w[slot] = wgt[id];
  }
  __syncthreads();
  const int slot = s_slot;
  const float* src = x + (size_t)t * DIM + threadIdx.x * 8;
  float4 a = *(const float4*)(src);
  float4 b = *(const float4*)(src + 4);
  uint4 o;
  o.x = (u32)f2bf(a.x) | ((u32)f2bf(a.y) << 16);
  o.y = (u32)f2bf(a.z) | ((u32)f2bf(a.w) << 16);
  o.z = (u32)f2bf(b.x) | ((u32)f2bf(b.y) << 16);
  o.w = (u32)f2bf(b.z) | ((u32)f2bf(b.w) << 16);
  *(uint4*)(Xg + (size_t)slot * DIM + threadIdx.x * 8) = o;
}

// ---------------- GEMM1: h = slot_w * silu(Xg@Wg) * (Xg@Wu), bf16 out ----------------
__global__ __launch_bounds__(256, 2) void moe_gemm1(
    const u16* __restrict__ Xg,
    const float* __restrict__ Wg_all, const float* __restrict__ Wu_all,
    const int* __restrict__ offs, const float* __restrict__ slot_w,
    u16* __restrict__ H)
{
  const int e = blockIdx.z;
  const int off = offs[e];
  const int cnt = offs[e + 1] - off;
  const int m0 = blockIdx.y * 128;
  if (m0 >= cnt) return;
  const int n0 = blockIdx.x * 128;

  const float* __restrict__ Wg = Wg_all + (size_t)e * DIM * FDIM;
  const float* __restrict__ Wu = Wu_all + (size_t)e * DIM * FDIM;

  __shared__ u16 As[128 * 32];
  __shared__ u16 Bg[128 * 32];
  __shared__ u16 Bu[128 * 32];

  const int tid = threadIdx.x;
  const int lane = tid & 63;
  const int wave = tid >> 6;
  const int wr = wave >> 1, wc = wave & 1;
  const int quad = lane >> 4, mr = lane & 15;

  f32x4 accg[4][4], accu[4][4];
  #pragma unroll
  for (int i = 0; i < 4; ++i)
    #pragma unroll
    for (int j = 0; j < 4; ++j) { accg[i][j] = {0.f,0.f,0.f,0.f}; accu[i][j] = {0.f,0.f,0.f,0.f}; }

  const u16* xbase = Xg + (size_t)(off + m0) * DIM;
  const int a_row = tid >> 2;
  const int a_k   = (tid & 3) * 8;

  for (int k0 = 0; k0 < DIM; k0 += 32) {
    // stage A (bf16, [m][k], 16B per thread x2)
    uint4 av0 = *(const uint4*)(xbase + (size_t)a_row * DIM + k0 + a_k);
    uint4 av1 = *(const uint4*)(xbase + (size_t)(a_row + 64) * DIM + k0 + a_k);
    *(uint4*)(&As[a_row * 32 + a_k]) = av0;
    *(uint4*)(&As[(a_row + 64) * 32 + a_k]) = av1;
    // stage B transposed to [n][k] with fp32->bf16 cvt; LDS-linear writes (conflict-free)
    #pragma unroll
    for (int j = 0; j < 4; ++j) {
      int linear = j * 256 + tid;
      int n = linear >> 3;
      int k = (linear & 7) * 4;
      const float* pg = Wg + (size_t)(k0 + k) * FDIM + (n0 + n);
      const float* pu = Wu + (size_t)(k0 + k) * FDIM + (n0 + n);
      float g0 = pg[0], g1 = pg[FDIM], g2 = pg[2 * FDIM], g3 = pg[3 * FDIM];
      float u0 = pu[0], u1 = pu[FDIM], u2 = pu[2 * FDIM], u3 = pu[3 * FDIM];
      uint2 gp, up;
      gp.x = (u32)f2bf(g0) | ((u32)f2bf(g1) << 16);
      gp.y = (u32)f2bf(g2) | ((u32)f2bf(g3) << 16);
      up.x = (u32)f2bf(u0) | ((u32)f2bf(u1) << 16);
      up.y = (u32)f2bf(u2) | ((u32)f2bf(u3) << 16);
      *(uint2*)(&Bg[n * 32 + k]) = gp;
      *(uint2*)(&Bu[n * 32 + k]) = up;
    }
    __syncthreads();
    bf16x8 af[4];
    #pragma unroll
    for (int mf = 0; mf < 4; ++mf) {
      B16 tmp; tmp.u = *(const uint4*)(&As[(wr * 64 + mf * 16 + mr) * 32 + quad * 8]);
      af[mf] = tmp.v;
    }
    #pragma unroll
    for (int nf = 0; nf < 4; ++nf) {
      B16 tg; tg.u = *(const uint4*)(&Bg[(wc * 64 + nf * 16 + mr) * 32 + quad * 8]);
      B16 tu; tu.u = *(const uint4*)(&Bu[(wc * 64 + nf * 16 + mr) * 32 + quad * 8]);
      #pragma unroll
      for (int mf = 0; mf < 4; ++mf) {
        accg[mf][nf] = __builtin_amdgcn_mfma_f32_16x16x32_bf16(af[mf], tg.v, accg[mf][nf], 0, 0, 0);
        accu[mf][nf] = __builtin_amdgcn_mfma_f32_16x16x32_bf16(af[mf], tu.v, accu[mf][nf], 0, 0, 0);
      }
    }
    __syncthreads();
  }

  // epilogue: h = w * silu(g) * u   (C/D: row = quad*4+r, col = mr)
  #pragma unroll
  for (int mf = 0; mf < 4; ++mf) {
    #pragma unroll
    for (int r = 0; r < 4; ++r) {
      int row = wr * 64 + mf * 16 + quad * 4 + r;
      if (m0 + row < cnt) {
        int slot = off + m0 + row;
        float w = slot_w[slot];
        #pragma unroll
        for (int nf = 0; nf < 4; ++nf) {
          float g = accg[mf][nf][r];
          float u = accu[mf][nf][r];
          float s = g / (1.f + __expf(-g));
          int col = n0 + wc * 64 + nf * 16 + mr;
          H[(size_t)slot * FDIM + col] = f2bf(w * s * u);
        }
      }
    }
  }
}

// ---------------- GEMM2: out[token] += H @ Wd ----------------
__global__ __launch_bounds__(256, 2) void moe_gemm2(
    const u16* __restrict__ H, const float* __restrict__ Wd_all,
    const int* __restrict__ offs, const int* __restrict__ slot_token,
    float* __restrict__ out)
{
  const int e = blockIdx.z;
  const int off = offs[e];
  const int cnt = offs[e + 1] - off;
  const int m0 = blockIdx.y * 128;
  if (m0 >= cnt) return;
  const int n0 = blockIdx.x * 128;

  const float* __restrict__ Wd = Wd_all + (size_t)e * FDIM * DIM;

  __shared__ u16 As[128 * 32];
  __shared__ u16 Bd[128 * 32];

  const int tid = threadIdx.x;
  const int lane = tid & 63;
  const int wave = tid >> 6;
  const int wr = wave >> 1, wc = wave & 1;
  const int quad = lane >> 4, mr = lane & 15;

  f32x4 acc[4][4];
  #pragma unroll
  for (int i = 0; i < 4; ++i)
    #pragma unroll
    for (int j = 0; j < 4; ++j) acc[i][j] = {0.f,0.f,0.f,0.f};

  const u16* hbase = H + (size_t)(off + m0) * FDIM;
  const int a_row = tid >> 2;
  const int a_k   = (tid & 3) * 8;

  for (int k0 = 0; k0 < FDIM; k0 += 32) {
    uint4 av0 = *(const uint4*)(hbase + (size_t)a_row * FDIM + k0 + a_k);
    uint4 av1 = *(const uint4*)(hbase + (size_t)(a_row + 64) * FDIM + k0 + a_k);
    *(uint4*)(&As[a_row * 32 + a_k]) = av0;
    *(uint4*)(&As[(a_row + 64) * 32 + a_k]) = av1;
    #pragma unroll
    for (int j = 0; j < 4; ++j) {
      int linear = j * 256 + tid;
      int n = linear >> 3;
      int k = (linear & 7) * 4;
      const float* pd = Wd + (size_t)(k0 + k) * DIM + (n0 + n);
      float d0 = pd[0], d1 = pd[DIM], d2 = pd[2 * DIM], d3 = pd[3 * DIM];
      uint2 dp;
      dp.x = (u32)f2bf(d0) | ((u32)f2bf(d1) << 16);
      dp.y = (u32)f2bf(d2) | ((u32)f2bf(d3) << 16);
      *(uint2*)(&Bd[n * 32 + k]) = dp;
    }
    __syncthreads();
    bf16x8 af[4];
    #pragma unroll
    for (int mf = 0; mf < 4; ++mf) {
      B16 tmp; tmp.u = *(const uint4*)(&As[(wr * 64 + mf * 16 + mr) * 32 + quad * 8]);
      af[mf] = tmp.v;
    }
    #pragma unroll
    for (int nf = 0; nf < 4; ++nf) {
      B16 tb; tb.u = *(const uint4*)(&Bd[(wc * 64 + nf * 16 + mr) * 32 + quad * 8]);
      #pragma unroll
      for (int mf = 0; mf < 4; ++mf)
        acc[mf][nf] = __builtin_amdgcn_mfma_f32_16x16x32_bf16(af[mf], tb.v, acc[mf][nf], 0, 0, 0);
    }
    __syncthreads();
  }

  #pragma unroll
  for (int mf = 0; mf < 4; ++mf) {
    #pragma unroll
    for (int r = 0; r < 4; ++r) {
      int row = wr * 64 + mf * 16 + quad * 4 + r;
      if (m0 + row < cnt) {
        int tok = slot_token[off + m0 + row];
        float* orow = out + (size_t)tok * DIM + n0;
        #pragma unroll
        for (int nf = 0; nf < 4; ++nf)
          atomicAdd(&orow[wc * 64 + nf * 16 + mr], acc[mf][nf][r]);
      }
    }
  }
}

extern "C" void kernel_launch(void* const* d_in, const int* in_sizes, int n_in,
                              void* d_out, int out_size, void* d_ws, size_t ws_size,
                              hipStream_t stream) {
  const float* x      = (const float*)d_in[0];
  const float* gate_w = (const float*)d_in[1];
  const float* w_gate = (const float*)d_in[2];
  const float* w_up   = (const float*)d_in[3];
  const float* w_down = (const float*)d_in[4];
  float* out = (float*)d_out;

  char* w = (char*)d_ws;
  int*   counts     = (int*)(w);
  int*   fill       = (int*)(w + 64);
  int*   offs       = (int*)(w + 128);
  int*   sel        = (int*)(w + 256);
  float* wgt        = (float*)(w + 256 + 16384);
  int*   slot_token = (int*)(w + 256 + 2 * 16384);
  float* slot_w     = (float*)(w + 256 + 3 * 16384);
  u16*   Xg         = (u16*)(w + 65792);                 // (4096+128) x 2048 bf16
  u16*   H          = (u16*)(w + 65792 + 17301504);      // (4096+128) x 1408 bf16

  hipMemsetAsync(d_ws, 0, 256, stream);                          // counts + fill
  hipMemsetAsync(d_out, 0, (size_t)out_size * sizeof(float), stream);

  router_kernel<<<T_TOK, 256, 0, stream>>>(x, gate_w, sel, wgt, counts);
  scan_kernel<<<1, 64, 0, stream>>>(counts, offs);
  gather_kernel<<<T_TOK * 2, 256, 0, stream>>>(x, sel, wgt, offs, fill, slot_token, slot_w, Xg);

  dim3 g1(FDIM / 128, 16, NEXP);      // (11, maxMtiles, E)
  moe_gemm1<<<g1, 256, 0, stream>>>(Xg, w_gate, w_up, offs, slot_w, H);

  dim3 g2(DIM / 128, 16, NEXP);       // (16, maxMtiles, E)
  moe_gemm2<<<g2, 256, 0, stream>>>(H, w_down, offs, slot_token, out);
}

// Round 2
// 572.806 us; speedup vs baseline: 1.4022x; 1.4022x over previous
//
#include <hip/hip_runtime.h>

typedef unsigned short u16;
typedef unsigned int   u32;

#define T_TOK 2048
#define DIM   2048
#define FDIM  1408
#define NEXP  8
#define SLOTS 4224   // 4096 + 128 tail headroom

typedef __bf16 bf16x8 __attribute__((ext_vector_type(8)));
typedef float  f32x4  __attribute__((ext_vector_type(4)));

union B16 { uint4 u; bf16x8 v; };

__device__ __forceinline__ u16 f2bf(float f) {
  union { float f; u32 u; } c; c.f = f;
  u32 u = c.u;
  u += 0x7FFFu + ((u >> 16) & 1u);   // round-to-nearest-even
  return (u16)(u >> 16);
}
__device__ __forceinline__ float bf2f(u16 h) {
  union { u32 u; float f; } c; c.u = (u32)h << 16; return c.f;
}

// async global->LDS, 16B per lane; lds base must be wave-uniform, data lands at base + lane*16
__device__ __forceinline__ void gld_lds16(const void* g, void* l) {
  __builtin_amdgcn_global_load_lds(
      (const __attribute__((address_space(1))) unsigned int*)g,
      (__attribute__((address_space(3))) unsigned int*)l, 16, 0, 0);
}

// ---------------- weight cvt fp32->bf16 + transpose [K][N] -> [N][K] ----------------
// z: 0..7 = w_gate experts, 8..15 = w_up, 16..23 = w_down
__global__ __launch_bounds__(256) void cvt_transpose(
    const float* __restrict__ Wg, const float* __restrict__ Wu, const float* __restrict__ Wd,
    u16* __restrict__ WgT, u16* __restrict__ WuT, u16* __restrict__ WdT)
{
  const int z = blockIdx.z;
  const int tensor = z >> 3;
  const int e = z & 7;
  const int Kt = (tensor == 2) ? FDIM : DIM;
  const int Nt = (tensor == 2) ? DIM : FDIM;
  const float* src;
  u16* dst;
  if (tensor == 0)      { src = Wg + (size_t)e * DIM * FDIM; dst = WgT + (size_t)e * DIM * FDIM; }
  else if (tensor == 1) { src = Wu + (size_t)e * DIM * FDIM; dst = WuT + (size_t)e * DIM * FDIM; }
  else                  { src = Wd + (size_t)e * DIM * FDIM; dst = WdT + (size_t)e * DIM * FDIM; }
  const int k0 = blockIdx.y * 64, n0 = blockIdx.x * 64;
  if (k0 >= Kt || n0 >= Nt) return;

  __shared__ u16 tile[64][64 + 4];   // +4 pad: conflict-light transposed reads
  const int tid = threadIdx.x;
  #pragma unroll
  for (int p = 0; p < 4; ++p) {                      // load 16 k-rows per pass, coalesced
    int k = p * 16 + (tid >> 4);
    int n = (tid & 15) * 4;
    float4 v = *(const float4*)(src + (size_t)(k0 + k) * Nt + n0 + n);
    uint2 o;
    o.x = (u32)f2bf(v.x) | ((u32)f2bf(v.y) << 16);
    o.y = (u32)f2bf(v.z) | ((u32)f2bf(v.w) << 16);
    *(uint2*)(&tile[k][n]) = o;
  }
  __syncthreads();
  #pragma unroll
  for (int p = 0; p < 4; ++p) {                      // store 64 n-rows, k-contiguous
    int n = tid >> 2;
    int k = (tid & 3) * 4 + p * 16;
    uint2 o;
    o.x = (u32)tile[k][n]     | ((u32)tile[k + 1][n] << 16);
    o.y = (u32)tile[k + 2][n] | ((u32)tile[k + 3][n] << 16);
    *(uint2*)(dst + (size_t)(n0 + n) * Kt + k0 + k) = o;
  }
}

// ---------------- router: fp32 logits, softmax top-2 renormalized ----------------
__global__ __launch_bounds__(256) void router_kernel(
    const float* __restrict__ x, const float* __restrict__ gate_w,
    int* __restrict__ sel, float* __restrict__ wgt, int* __restrict__ counts)
{
  const int t = blockIdx.x;
  const float* xr = x + (size_t)t * DIM;
  float acc[NEXP];
  #pragma unroll
  for (int e = 0; e < NEXP; ++e) acc[e] = 0.f;
  for (int d = threadIdx.x; d < DIM; d += 256) {
    float xv = xr[d];
    #pragma unroll
    for (int e = 0; e < NEXP; ++e) acc[e] += xv * gate_w[e * DIM + d];
  }
  #pragma unroll
  for (int e = 0; e < NEXP; ++e) {
    #pragma unroll
    for (int s = 32; s > 0; s >>= 1) acc[e] += __shfl_down(acc[e], s, 64);
  }
  __shared__ float red[4][NEXP];
  const int lane = threadIdx.x & 63, wv = threadIdx.x >> 6;
  if (lane == 0) {
    #pragma unroll
    for (int e = 0; e < NEXP; ++e) red[wv][e] = acc[e];
  }
  __syncthreads();
  if (threadIdx.x == 0) {
    float l[NEXP];
    #pragma unroll
    for (int e = 0; e < NEXP; ++e) l[e] = red[0][e] + red[1][e] + red[2][e] + red[3][e];
    int i0 = 0;
    #pragma unroll
    for (int e = 1; e < NEXP; ++e) if (l[e] > l[i0]) i0 = e;   // lowest index wins ties
    int i1 = (i0 == 0) ? 1 : 0;
    #pragma unroll
    for (int e = 0; e < NEXP; ++e) if (e != i0 && l[e] > l[i1]) i1 = e;
    float w0 = 1.f / (1.f + __expf(l[i1] - l[i0]));   // p0/(p0+p1)
    sel[t * 2] = i0; sel[t * 2 + 1] = i1;
    wgt[t * 2] = w0; wgt[t * 2 + 1] = 1.f - w0;
    atomicAdd(&counts[i0], 1);
    atomicAdd(&counts[i1], 1);
  }
}

__global__ void scan_kernel(const int* __restrict__ counts, int* __restrict__ offs)
{
  if (threadIdx.x == 0) {
    int s = 0;
    for (int e = 0; e < NEXP; ++e) { offs[e] = s; s += counts[e]; }
    offs[NEXP] = s;
  }
}

// ---------------- gather: slot assignment + x -> bf16 segments ----------------
__global__ __launch_bounds__(256) void gather_kernel(
    const float* __restrict__ x, const int* __restrict__ sel, const float* __restrict__ wgt,
    const int* __restrict__ offs, int* __restrict__ fill,
    int* __restrict__ slot_token, float* __restrict__ slot_w,
    int* __restrict__ tok_slots, u16* __restrict__ Xg)
{
  const int id = blockIdx.x;       // t*2 + k
  const int t = id >> 1;
  __shared__ int s_slot;
  if (threadIdx.x == 0) {
    int e = sel[id];
    int pos = atomicAdd(&fill[e], 1);
    int slot = offs[e] + pos;
    s_slot = slot;
    slot_token[slot] = t;
    slot_w[slot] = wgt[id];
    tok_slots[id] = slot;
  }
  __syncthreads();
  const int slot = s_slot;
  const float* src = x + (size_t)t * DIM + threadIdx.x * 8;
  float4 a = *(const float4*)(src);
  float4 b = *(const float4*)(src + 4);
  uint4 o;
  o.x = (u32)f2bf(a.x) | ((u32)f2bf(a.y) << 16);
  o.y = (u32)f2bf(a.z) | ((u32)f2bf(a.w) << 16);
  o.z = (u32)f2bf(b.x) | ((u32)f2bf(b.y) << 16);
  o.w = (u32)f2bf(b.z) | ((u32)f2bf(b.w) << 16);
  *(uint4*)(Xg + (size_t)slot * DIM + threadIdx.x * 8) = o;
}

// ---------------- GEMM1: H = slot_w * silu(Xg@Wg) * (Xg@Wu) ----------------
// tiles: BM=128, BN=64, BK=32; 4 waves, each 64m x 32n; B pre-transposed bf16 [n][k]
__global__ __launch_bounds__(256, 2) void moe_gemm1(
    const u16* __restrict__ Xg,
    const u16* __restrict__ WgT, const u16* __restrict__ WuT,
    const int* __restrict__ offs, const float* __restrict__ slot_w,
    u16* __restrict__ H)
{
  const int e = blockIdx.z;
  const int off = offs[e];
  const int cnt = offs[e + 1] - off;
  const int m0 = blockIdx.y * 128;
  if (m0 >= cnt) return;
  const int n0 = blockIdx.x * 64;

  const u16* __restrict__ Bg_g = WgT + (size_t)e * (size_t)FDIM * DIM;
  const u16* __restrict__ Bu_g = WuT + (size_t)e * (size_t)FDIM * DIM;

  __shared__ __align__(16) u16 As[128 * 32];
  __shared__ __align__(16) u16 Bgs[64 * 32];
  __shared__ __align__(16) u16 Bus[64 * 32];

  const int tid = threadIdx.x;
  const int lane = tid & 63, wave = tid >> 6;
  const int wr = wave >> 1, wc = wave & 1;
  const int quad = lane >> 4, mr = lane & 15;

  // per-lane global pointers for async staging (advance by k0 each iter)
  const u16* agp0 = Xg + (size_t)(off + m0 + wave * 32 + (lane >> 2)) * DIM + (lane & 3) * 8;
  const u16* agp1 = agp0 + (size_t)16 * DIM;
  const u16* bgp  = Bg_g + (size_t)(n0 + wave * 16 + (lane >> 2)) * DIM + (lane & 3) * 8;
  const u16* bup  = Bu_g + (size_t)(n0 + wave * 16 + (lane >> 2)) * DIM + (lane & 3) * 8;
  // wave-uniform LDS bases
  u16* asl0 = As  + (wave * 32) * 32;
  u16* asl1 = As  + (wave * 32 + 16) * 32;
  u16* bgl  = Bgs + (wave * 16) * 32;
  u16* bul  = Bus + (wave * 16) * 32;

  f32x4 accg[4][2], accu[4][2];
  #pragma unroll
  for (int i = 0; i < 4; ++i)
    #pragma unroll
    for (int j = 0; j < 2; ++j) { accg[i][j] = {0.f,0.f,0.f,0.f}; accu[i][j] = {0.f,0.f,0.f,0.f}; }

  for (int k0 = 0; k0 < DIM; k0 += 32) {
    gld_lds16(agp0 + k0, asl0);
    gld_lds16(agp1 + k0, asl1);
    gld_lds16(bgp  + k0, bgl);
    gld_lds16(bup  + k0, bul);
    __syncthreads();
    bf16x8 af[4], bgf[2], buf2[2];
    #pragma unroll
    for (int mf = 0; mf < 4; ++mf) {
      B16 t_; t_.u = *(const uint4*)(&As[(wr * 64 + mf * 16 + mr) * 32 + quad * 8]);
      af[mf] = t_.v;
    }
    #pragma unroll
    for (int nf = 0; nf < 2; ++nf) {
      B16 tg; tg.u = *(const uint4*)(&Bgs[(wc * 32 + nf * 16 + mr) * 32 + quad * 8]);
      B16 tu; tu.u = *(const uint4*)(&Bus[(wc * 32 + nf * 16 + mr) * 32 + quad * 8]);
      bgf[nf] = tg.v; buf2[nf] = tu.v;
    }
    #pragma unroll
    for (int nf = 0; nf < 2; ++nf)
      #pragma unroll
      for (int mf = 0; mf < 4; ++mf) {
        accg[mf][nf] = __builtin_amdgcn_mfma_f32_16x16x32_bf16(af[mf], bgf[nf],  accg[mf][nf], 0, 0, 0);
        accu[mf][nf] = __builtin_amdgcn_mfma_f32_16x16x32_bf16(af[mf], buf2[nf], accu[mf][nf], 0, 0, 0);
      }
    __syncthreads();
  }

  #pragma unroll
  for (int mf = 0; mf < 4; ++mf) {
    #pragma unroll
    for (int r = 0; r < 4; ++r) {
      int row = wr * 64 + mf * 16 + quad * 4 + r;
      if (m0 + row < cnt) {
        int slot = off + m0 + row;
        float w = slot_w[slot];
        #pragma unroll
        for (int nf = 0; nf < 2; ++nf) {
          float g = accg[mf][nf][r];
          float u = accu[mf][nf][r];
          float s = g / (1.f + __expf(-g));
          H[(size_t)slot * FDIM + n0 + wc * 32 + nf * 16 + mr] = f2bf(w * s * u);
        }
      }
    }
  }
}

// ---------------- GEMM2: Ho[slot] = H[slot] @ Wd  (per-slot, no atomics) ----------------
__global__ __launch_bounds__(256, 2) void moe_gemm2(
    const u16* __restrict__ H, const u16* __restrict__ WdT,
    const int* __restrict__ offs, u16* __restrict__ Ho)
{
  const int e = blockIdx.z;
  const int off = offs[e];
  const int cnt = offs[e + 1] - off;
  const int m0 = blockIdx.y * 128;
  if (m0 >= cnt) return;
  const int n0 = blockIdx.x * 64;

  const u16* __restrict__ Bd_g = WdT + (size_t)e * (size_t)DIM * FDIM;  // [d][f], K=FDIM

  __shared__ __align__(16) u16 As[128 * 32];
  __shared__ __align__(16) u16 Bds[64 * 32];

  const int tid = threadIdx.x;
  const int lane = tid & 63, wave = tid >> 6;
  const int wr = wave >> 1, wc = wave & 1;
  const int quad = lane >> 4, mr = lane & 15;

  const u16* agp0 = H + (size_t)(off + m0 + wave * 32 + (lane >> 2)) * FDIM + (lane & 3) * 8;
  const u16* agp1 = agp0 + (size_t)16 * FDIM;
  const u16* bdp  = Bd_g + (size_t)(n0 + wave * 16 + (lane >> 2)) * FDIM + (lane & 3) * 8;
  u16* asl0 = As  + (wave * 32) * 32;
  u16* asl1 = As  + (wave * 32 + 16) * 32;
  u16* bdl  = Bds + (wave * 16) * 32;

  f32x4 acc[4][2];
  #pragma unroll
  for (int i = 0; i < 4; ++i)
    #pragma unroll
    for (int j = 0; j < 2; ++j) acc[i][j] = {0.f,0.f,0.f,0.f};

  for (int k0 = 0; k0 < FDIM; k0 += 32) {
    gld_lds16(agp0 + k0, asl0);
    gld_lds16(agp1 + k0, asl1);
    gld_lds16(bdp  + k0, bdl);
    __syncthreads();
    bf16x8 af[4], bdf[2];
    #pragma unroll
    for (int mf = 0; mf < 4; ++mf) {
      B16 t_; t_.u = *(const uint4*)(&As[(wr * 64 + mf * 16 + mr) * 32 + quad * 8]);
      af[mf] = t_.v;
    }
    #pragma unroll
    for (int nf = 0; nf < 2; ++nf) {
      B16 tb; tb.u = *(const uint4*)(&Bds[(wc * 32 + nf * 16 + mr) * 32 + quad * 8]);
      bdf[nf] = tb.v;
    }
    #pragma unroll
    for (int nf = 0; nf < 2; ++nf)
      #pragma unroll
      for (int mf = 0; mf < 4; ++mf)
        acc[mf][nf] = __builtin_amdgcn_mfma_f32_16x16x32_bf16(af[mf], bdf[nf], acc[mf][nf], 0, 0, 0);
    __syncthreads();
  }

  #pragma unroll
  for (int mf = 0; mf < 4; ++mf) {
    #pragma unroll
    for (int r = 0; r < 4; ++r) {
      int row = wr * 64 + mf * 16 + quad * 4 + r;
      if (m0 + row < cnt) {
        int slot = off + m0 + row;
        #pragma unroll
        for (int nf = 0; nf < 2; ++nf)
          Ho[(size_t)slot * DIM + n0 + wc * 32 + nf * 16 + mr] = f2bf(acc[mf][nf][r]);
      }
    }
  }
}

// ---------------- combine: out[t] = Ho[slot0(t)] + Ho[slot1(t)] ----------------
__global__ __launch_bounds__(256) void combine_kernel(
    const u16* __restrict__ Ho, const int* __restrict__ tok_slots,
    float* __restrict__ out)
{
  const int t = blockIdx.x;
  const int s0 = tok_slots[t * 2], s1 = tok_slots[t * 2 + 1];
  const int base = threadIdx.x * 8;
  uint4 a = *(const uint4*)(Ho + (size_t)s0 * DIM + base);
  uint4 b = *(const uint4*)(Ho + (size_t)s1 * DIM + base);
  float* o = out + (size_t)t * DIM + base;
  float4 lo, hi;
  lo.x = bf2f((u16)(a.x & 0xFFFF)) + bf2f((u16)(b.x & 0xFFFF));
  lo.y = bf2f((u16)(a.x >> 16))    + bf2f((u16)(b.x >> 16));
  lo.z = bf2f((u16)(a.y & 0xFFFF)) + bf2f((u16)(b.y & 0xFFFF));
  lo.w = bf2f((u16)(a.y >> 16))    + bf2f((u16)(b.y >> 16));
  hi.x = bf2f((u16)(a.z & 0xFFFF)) + bf2f((u16)(b.z & 0xFFFF));
  hi.y = bf2f((u16)(a.z >> 16))    + bf2f((u16)(b.z >> 16));
  hi.z = bf2f((u16)(a.w & 0xFFFF)) + bf2f((u16)(b.w & 0xFFFF));
  hi.w = bf2f((u16)(a.w >> 16))    + bf2f((u16)(b.w >> 16));
  *(float4*)(o)     = lo;
  *(float4*)(o + 4) = hi;
}

extern "C" void kernel_launch(void* const* d_in, const int* in_sizes, int n_in,
                              void* d_out, int out_size, void* d_ws, size_t ws_size,
                              hipStream_t stream) {
  const float* x      = (const float*)d_in[0];
  const float* gate_w = (const float*)d_in[1];
  const float* w_gate = (const float*)d_in[2];
  const float* w_up   = (const float*)d_in[3];
  const float* w_down = (const float*)d_in[4];
  float* out = (float*)d_out;

  char* w = (char*)d_ws;
  // control block
  int*   counts     = (int*)(w + 0);
  int*   fill       = (int*)(w + 64);
  int*   offs       = (int*)(w + 128);
  int*   sel        = (int*)(w + 4096);
  float* wgt        = (float*)(w + 4096 + 16384);
  int*   tok_slots  = (int*)(w + 4096 + 2 * 16384);
  int*   slot_token = (int*)(w + 4096 + 3 * 16384);
  float* slot_w     = (float*)(w + 4096 + 3 * 16384 + 17408);
  // big buffers (16B aligned)
  size_t o = 131072;
  u16* Xg  = (u16*)(w + o); o += (size_t)SLOTS * DIM  * 2;   // 17.3 MB
  u16* H   = (u16*)(w + o); o += (size_t)SLOTS * FDIM * 2;   // 11.9 MB
  u16* Ho  = (u16*)(w + o); o += (size_t)SLOTS * DIM  * 2;   // 17.3 MB
  u16* WgT = (u16*)(w + o); o += (size_t)NEXP * DIM * FDIM * 2;  // 46.1 MB
  u16* WuT = (u16*)(w + o); o += (size_t)NEXP * DIM * FDIM * 2;
  u16* WdT = (u16*)(w + o); o += (size_t)NEXP * DIM * FDIM * 2;
  // total ~186 MB

  hipMemsetAsync(d_ws, 0, 256, stream);   // counts + fill

  dim3 gc(32, 32, 24);
  cvt_transpose<<<gc, 256, 0, stream>>>(w_gate, w_up, w_down, WgT, WuT, WdT);

  router_kernel<<<T_TOK, 256, 0, stream>>>(x, gate_w, sel, wgt, counts);
  scan_kernel<<<1, 64, 0, stream>>>(counts, offs);
  gather_kernel<<<T_TOK * 2, 256, 0, stream>>>(x, sel, wgt, offs, fill,
                                               slot_token, slot_w, tok_slots, Xg);

  dim3 g1(FDIM / 64, 32, NEXP);   // (22, maxMtiles, E)
  moe_gemm1<<<g1, 256, 0, stream>>>(Xg, WgT, WuT, offs, slot_w, H);

  dim3 g2(DIM / 64, 32, NEXP);    // (32, maxMtiles, E)
  moe_gemm2<<<g2, 256, 0, stream>>>(H, WdT, offs, Ho);

  combine_kernel<<<T_TOK, 256, 0, stream>>>(Ho, tok_slots, out);
}